// Round 1
// baseline (745.383 us; speedup 1.0000x reference)
//
#include <hip/hip_runtime.h>

// Flash-style cross-attention, B=32, Tq=512, Tk=2048, D=512, fp32 in/out.
// scores = Q K^T (no scaling) -> softmax -> context = P V  (V == K tensor).
//
// Round-1 design:
//  - bf16 MFMA (16x16x32) with split-bf16 (hi/lo) 3-product QK^T for accuracy
//    (scores ~ +-80 and softmax unscaled => need ~fp24-level dot products).
//  - One block = (batch b, 16 q rows). grid(32 batches, 32 qtiles): batch is
//    blockIdx.x so all q-tiles of one batch share an XCD (linear%8) -> L2 reuse
//    of the 4 MB encoder block.
//  - 4 waves; K tile (16 keys x 512 d) staged fp32 in LDS (~39 KB total LDS,
//    4 blocks/CU). Q frags (hi/lo) live in registers per-wave (d-quad).
//  - QK^T: wave w covers d in [w*128, w*128+128); partial S in LDS; wave 0 does
//    online softmax (one lane per q row), writes P (bf16) + alpha.
//  - PV: 16x16x32 MFMA with upper 16 k-slots zeroed (NK=16), O acc in regs
//    (16 rows x 128 cols per wave), rescaled by alpha each tile.

#define BATCH 32
#define TQ 512
#define TK 2048
#define DIM 512
#define MQ 16
#define NK 16
#define KPAD (DIM + 4)
#define SPAD (NK + 4)
#define PPAD (NK + 4)

typedef __attribute__((ext_vector_type(8))) short short8;
typedef __attribute__((ext_vector_type(4))) short short4v;
typedef __attribute__((ext_vector_type(4))) float float4v;

__device__ __forceinline__ short bf16_rne(float f) {
  unsigned u = __float_as_uint(f);
  unsigned r = (u + 0x7FFFu + ((u >> 16) & 1u)) >> 16;
  return (short)r;
}

// f = hi + lo (both bf16), hi truncated, lo RNE: ~16-17 mantissa bits total.
__device__ __forceinline__ void split2(float f, short& hi, short& lo) {
  unsigned u = __float_as_uint(f);
  hi = (short)(u >> 16);
  float fh = __uint_as_float(u & 0xFFFF0000u);
  lo = bf16_rne(f - fh);
}

__global__ __launch_bounds__(256, 4)
void attn_flash(const float* __restrict__ dec, const float* __restrict__ enc,
                float* __restrict__ out) {
  const int b = blockIdx.x;
  const int q0 = blockIdx.y * MQ;
  const int tid = threadIdx.x;
  const int wave = tid >> 6;
  const int lane = tid & 63;
  const int quad = lane >> 4;
  const int l16 = lane & 15;

  __shared__ __align__(16) float Kf[NK][KPAD];       // fp32 K tile
  __shared__ __align__(16) float Sp[4][MQ][SPAD];    // per-wave S partials
  __shared__ __align__(16) short Pl[MQ][PPAD];       // P in bf16
  __shared__ __align__(16) float alpha_s[MQ];
  __shared__ __align__(16) float l_s[MQ];

  // ---- Q fragments (hi/lo bf16) for this wave's 128-wide d-quad ----
  // a-frag layout (16x16x32): lane holds A[m=lane&15][k=quad*8+j], j=0..7
  short8 qhi[4], qlo[4];
  {
    const float* qrow =
        dec + ((size_t)b * TQ + (q0 + l16)) * DIM + wave * 128 + quad * 8;
#pragma unroll
    for (int s = 0; s < 4; ++s) {
      float4v v0 = *(const float4v*)(qrow + s * 32);
      float4v v1 = *(const float4v*)(qrow + s * 32 + 4);
#pragma unroll
      for (int j = 0; j < 4; ++j) {
        short h, l;
        split2(v0[j], h, l); qhi[s][j] = h; qlo[s][j] = l;
        split2(v1[j], h, l); qhi[s][j + 4] = h; qlo[s][j + 4] = l;
      }
    }
  }

  float4v acc[8];
#pragma unroll
  for (int t = 0; t < 8; ++t) acc[t] = float4v{0.f, 0.f, 0.f, 0.f};

  float m_r = -INFINITY, l_r = 0.0f;  // meaningful in wave 0, lanes 0..15

  const int krow_t = tid >> 4;          // 0..15
  const int kcol_t = (tid & 15) * 4;    // float4 column base
  const float* encb = enc + (size_t)b * TK * DIM;

  for (int k0 = 0; k0 < TK; k0 += NK) {
    __syncthreads();  // prev iter done with Kf/Pl/alpha_s
    // ---- stage K tile (fp32, coalesced float4) ----
    {
      const float* kr = encb + (size_t)(k0 + krow_t) * DIM + kcol_t;
#pragma unroll
      for (int i = 0; i < 8; ++i) {
        float4v v = *(const float4v*)(kr + i * 64);
        *(float4v*)&Kf[krow_t][kcol_t + i * 64] = v;
      }
    }
    __syncthreads();

    // ---- QK^T partial over this wave's d-quad (split-bf16, 3 products) ----
    {
      float4v sacc = float4v{0.f, 0.f, 0.f, 0.f};
#pragma unroll
      for (int s = 0; s < 4; ++s) {
        const float* kp = &Kf[l16][wave * 128 + s * 32 + quad * 8];
        float4v k0v = *(const float4v*)kp;
        float4v k1v = *(const float4v*)(kp + 4);
        short8 khi, klo;
#pragma unroll
        for (int j = 0; j < 4; ++j) {
          short h, l;
          split2(k0v[j], h, l); khi[j] = h; klo[j] = l;
          split2(k1v[j], h, l); khi[j + 4] = h; klo[j + 4] = l;
        }
        sacc = __builtin_amdgcn_mfma_f32_16x16x32_bf16(qhi[s], khi, sacc, 0, 0, 0);
        sacc = __builtin_amdgcn_mfma_f32_16x16x32_bf16(qhi[s], klo, sacc, 0, 0, 0);
        sacc = __builtin_amdgcn_mfma_f32_16x16x32_bf16(qlo[s], khi, sacc, 0, 0, 0);
      }
      // C/D layout: col(key)=lane&15, row(q)=quad*4+r
#pragma unroll
      for (int r = 0; r < 4; ++r) Sp[wave][quad * 4 + r][l16] = sacc[r];
    }
    __syncthreads();

    // ---- online softmax: wave 0, one lane per q row ----
    if (wave == 0 && lane < 16) {
      float sv[16];
#pragma unroll
      for (int g = 0; g < 4; ++g) {
        float4v t0 = *(const float4v*)&Sp[0][lane][g * 4];
        float4v t1 = *(const float4v*)&Sp[1][lane][g * 4];
        float4v t2 = *(const float4v*)&Sp[2][lane][g * 4];
        float4v t3 = *(const float4v*)&Sp[3][lane][g * 4];
        float4v t = t0 + t1 + t2 + t3;
#pragma unroll
        for (int j = 0; j < 4; ++j) sv[g * 4 + j] = t[j];
      }
      float mx = sv[0];
#pragma unroll
      for (int c = 1; c < 16; ++c) mx = fmaxf(mx, sv[c]);
      float mnew = fmaxf(m_r, mx);
      float al = __expf(m_r - mnew);  // first tile: exp(-inf)=0
      float sum = 0.0f;
      short ph[16];
#pragma unroll
      for (int c = 0; c < 16; ++c) {
        float p = __expf(sv[c] - mnew);
        sum += p;
        ph[c] = bf16_rne(p);
      }
      l_r = l_r * al + sum;
      m_r = mnew;
      alpha_s[lane] = al;
#pragma unroll
      for (int g = 0; g < 4; ++g) {
        short4v w = {ph[g * 4], ph[g * 4 + 1], ph[g * 4 + 2], ph[g * 4 + 3]};
        *(short4v*)&Pl[lane][g * 4] = w;
      }
    }
    __syncthreads();

    // ---- PV: rescale O by alpha, accumulate P·V (upper 16 k-slots zero) ----
    {
      short8 pfrag = {0, 0, 0, 0, 0, 0, 0, 0};
      if (quad < 2) {
        const short* pp = &Pl[l16][quad * 8];
        short4v a0 = *(const short4v*)pp;
        short4v a1 = *(const short4v*)(pp + 4);
        pfrag[0] = a0[0]; pfrag[1] = a0[1]; pfrag[2] = a0[2]; pfrag[3] = a0[3];
        pfrag[4] = a1[0]; pfrag[5] = a1[1]; pfrag[6] = a1[2]; pfrag[7] = a1[3];
      }
      float4v alf = *(const float4v*)&alpha_s[quad * 4];
#pragma unroll
      for (int t = 0; t < 8; ++t) {
        const int dc = wave * 128 + t * 16 + l16;
        short8 vfrag = {0, 0, 0, 0, 0, 0, 0, 0};
        if (quad < 2) {
#pragma unroll
          for (int j = 0; j < 8; ++j) vfrag[j] = bf16_rne(Kf[quad * 8 + j][dc]);
        }
        acc[t] *= alf;  // acc[t][r] is row quad*4+r; alf[r] matches
        acc[t] = __builtin_amdgcn_mfma_f32_16x16x32_bf16(pfrag, vfrag, acc[t], 0, 0, 0);
      }
    }
  }

  if (wave == 0 && lane < 16) l_s[lane] = l_r;
  __syncthreads();

  // ---- epilogue: O / l, store ----
  {
    float4v lv = *(const float4v*)&l_s[quad * 4];
    float4v linv = {1.0f / lv[0], 1.0f / lv[1], 1.0f / lv[2], 1.0f / lv[3]};
#pragma unroll
    for (int t = 0; t < 8; ++t) {
      size_t base = ((size_t)b * TQ + q0 + quad * 4) * DIM + wave * 128 + t * 16 + l16;
#pragma unroll
      for (int r = 0; r < 4; ++r) {
        out[base + (size_t)r * DIM] = acc[t][r] * linv[r];
      }
    }
  }
}

extern "C" void kernel_launch(void* const* d_in, const int* in_sizes, int n_in,
                              void* d_out, int out_size, void* d_ws, size_t ws_size,
                              hipStream_t stream) {
  const float* dec = (const float*)d_in[0];
  const float* enc = (const float*)d_in[1];
  float* out = (float*)d_out;
  dim3 grid(BATCH, TQ / MQ);
  attn_flash<<<grid, 256, 0, stream>>>(dec, enc, out);
}

// Round 3
// 541.734 us; speedup vs baseline: 1.3759x; 1.3759x over previous
//
#include <hip/hip_runtime.h>

// Flash-style cross-attention, B=32, Tq=512, Tk=2048, D=512, fp32 in/out.
// Round 3 = round-2 design with the cvt_pkrtz return-type fix.
//  - QK^T = Qhi(f16,RNE) x (Khi + Klo) : 2 MFMAs, score err ~3e-3.
//  - K tile converted ONCE per block per tile into LDS:
//      Khi/Klo in fragment-major layout (lane-linear b128 read/write),
//      Vt[d][k] transposed f16 copy for PV B-frags (b128 reads).
//  - MQ=32 (2 m-tiles/wave), NK=16, 4 waves split D into quarters.
//  - Global loads for tile t+1 prefetched into regs before barriers.
//  - grid: 512 linear blocks; b = 4*(id&7) + ((id>>3)&3) so XCD x serves
//    batches [4x,4x+4) -> L2 locality for enc.

#define BATCH 32
#define TQ 512
#define TK 2048
#define DIM 512
#define MQ 32
#define NK 16
#define NKT (TK / NK)   // 128 k-tiles
#define PPAD 24         // Pl row stride (halfs), 48B: 16B-aligned

typedef __attribute__((ext_vector_type(8))) _Float16 half8;
typedef __attribute__((ext_vector_type(2))) _Float16 half2v;
typedef __attribute__((ext_vector_type(4))) float float4v;

__device__ __forceinline__ half2v pkrtz(float a, float b) {
  auto r = __builtin_amdgcn_cvt_pkrtz(a, b);  // __fp16 x2
  half2v o;
  o[0] = (_Float16)r[0];
  o[1] = (_Float16)r[1];
  return o;
}

__device__ __forceinline__ void split8(float4v a, float4v b, half8& hi, half8& lo) {
  float f[8];
#pragma unroll
  for (int j = 0; j < 4; ++j) { f[j] = a[j]; f[4 + j] = b[j]; }
#pragma unroll
  for (int p = 0; p < 4; ++p) {
    half2v h = pkrtz(f[2 * p], f[2 * p + 1]);
    half2v l = pkrtz(f[2 * p] - (float)h[0], f[2 * p + 1] - (float)h[1]);
    hi[2 * p] = h[0]; hi[2 * p + 1] = h[1];
    lo[2 * p] = l[0]; lo[2 * p + 1] = l[1];
  }
}

__global__ __launch_bounds__(256, 2)
void attn_flash2(const float* __restrict__ dec, const float* __restrict__ enc,
                 float* __restrict__ out) {
  const int id = blockIdx.x;
  const int b = ((id & 7) << 2) + ((id >> 3) & 3);  // XCD-clustered batches
  const int q0 = (id >> 5) * MQ;
  const int tid = threadIdx.x;
  const int wave = tid >> 6;
  const int lane = tid & 63;
  const int quad = lane >> 4;
  const int l16 = lane & 15;

  // K tile fragment-major: chunk s (16 of them: d=32s..32s+32), 64 slots of 8
  // halfs; slot = quad*16 + key holds K[key][32s+8*quad .. +8].
  __shared__ __align__(16) _Float16 KhiL[16 * 64 * 8];   // 16 KB
  __shared__ __align__(16) _Float16 KloL[16 * 64 * 8];   // 16 KB
  __shared__ __align__(16) _Float16 VtL[DIM * NK];       // 16 KB, Vt[d][k]
  __shared__ __align__(16) float Sp[4][MQ][16];          // 8 KB
  __shared__ __align__(16) _Float16 PlL[MQ * PPAD];      // 1.5 KB
  __shared__ __align__(16) float alpha_s[MQ];
  __shared__ __align__(16) float l_s[MQ];

  // ---- Q fragments: single f16 (RNE), wave covers d-quarter [w*128, +128) ----
  half8 qh[2][4];
#pragma unroll
  for (int mt = 0; mt < 2; ++mt) {
    const float* qrow =
        dec + ((size_t)b * TQ + (q0 + mt * 16 + l16)) * DIM + wave * 128 + quad * 8;
#pragma unroll
    for (int s = 0; s < 4; ++s) {
      float4v v0 = *(const float4v*)(qrow + s * 32);
      float4v v1 = *(const float4v*)(qrow + s * 32 + 4);
#pragma unroll
      for (int j = 0; j < 4; ++j) {
        qh[mt][s][j] = (_Float16)v0[j];       // RNE
        qh[mt][s][j + 4] = (_Float16)v1[j];
      }
    }
  }

  float4v acc[2][8];
#pragma unroll
  for (int mt = 0; mt < 2; ++mt)
#pragma unroll
    for (int t = 0; t < 8; ++t) acc[mt][t] = float4v{0.f, 0.f, 0.f, 0.f};

  float m_r = -INFINITY, l_r = 0.0f;  // waves 0/1, lanes<16

  const float* encb = enc + (size_t)b * TK * DIM;
  const int key = tid & 15;
  const int drow = tid >> 4;  // dbase = drow*8 + i*128

  // ---- prefetch tile 0 ----
  float4v pf[8];
  {
    const float* kp = encb + (size_t)key * DIM + drow * 8;
#pragma unroll
    for (int i = 0; i < 4; ++i) {
      pf[2 * i] = *(const float4v*)(kp + i * 128);
      pf[2 * i + 1] = *(const float4v*)(kp + i * 128 + 4);
    }
  }

  for (int kt = 0; kt < NKT; ++kt) {
    // ---- stage tile kt from prefetch regs: convert + write LDS ----
#pragma unroll
    for (int i = 0; i < 4; ++i) {
      half8 hi8, lo8;
      split8(pf[2 * i], pf[2 * i + 1], hi8, lo8);
      const int dbase = drow * 8 + i * 128;
      const int sg = (drow >> 2) + i * 4;           // chunk index
      const int slot = ((drow & 3) << 4) + key;     // lane-linear per wave
      *(half8*)&KhiL[(sg * 64 + slot) * 8] = hi8;
      *(half8*)&KloL[(sg * 64 + slot) * 8] = lo8;
#pragma unroll
      for (int j = 0; j < 8; ++j) VtL[(dbase + j) * NK + key] = hi8[j];
    }
    // ---- prefetch tile kt+1 (wraps at end; harmless re-read) ----
    {
      const int k0n = ((kt + 1) & (NKT - 1)) * NK;
      const float* kp = encb + (size_t)(k0n + key) * DIM + drow * 8;
#pragma unroll
      for (int i = 0; i < 4; ++i) {
        pf[2 * i] = *(const float4v*)(kp + i * 128);
        pf[2 * i + 1] = *(const float4v*)(kp + i * 128 + 4);
      }
    }
    __syncthreads();

    // ---- QK^T over this wave's d-quarter: 2 products (hi + lo) ----
    {
      float4v sacc0 = float4v{0.f, 0.f, 0.f, 0.f};
      float4v sacc1 = float4v{0.f, 0.f, 0.f, 0.f};
#pragma unroll
      for (int s = 0; s < 4; ++s) {
        half8 kh = *(const half8*)&KhiL[(((wave << 2) + s) * 64 + lane) * 8];
        half8 kl = *(const half8*)&KloL[(((wave << 2) + s) * 64 + lane) * 8];
        sacc0 = __builtin_amdgcn_mfma_f32_16x16x32_f16(qh[0][s], kh, sacc0, 0, 0, 0);
        sacc0 = __builtin_amdgcn_mfma_f32_16x16x32_f16(qh[0][s], kl, sacc0, 0, 0, 0);
        sacc1 = __builtin_amdgcn_mfma_f32_16x16x32_f16(qh[1][s], kh, sacc1, 0, 0, 0);
        sacc1 = __builtin_amdgcn_mfma_f32_16x16x32_f16(qh[1][s], kl, sacc1, 0, 0, 0);
      }
#pragma unroll
      for (int r = 0; r < 4; ++r) {
        Sp[wave][(quad << 2) + r][l16] = sacc0[r];
        Sp[wave][16 + (quad << 2) + r][l16] = sacc1[r];
      }
    }
    __syncthreads();

    // ---- online softmax: waves 0/1, one lane per q row ----
    if (wave < 2 && lane < 16) {
      const int row = (wave << 4) + lane;
      float sv[16];
#pragma unroll
      for (int g = 0; g < 4; ++g) {
        float4v t0 = *(const float4v*)&Sp[0][row][g * 4];
        float4v t1 = *(const float4v*)&Sp[1][row][g * 4];
        float4v t2 = *(const float4v*)&Sp[2][row][g * 4];
        float4v t3 = *(const float4v*)&Sp[3][row][g * 4];
        float4v t = (t0 + t1) + (t2 + t3);
#pragma unroll
        for (int j = 0; j < 4; ++j) sv[g * 4 + j] = t[j];
      }
      float mx = sv[0];
#pragma unroll
      for (int c = 1; c < 16; ++c) mx = fmaxf(mx, sv[c]);
      const float mnew = fmaxf(m_r, mx);
      const float al = __expf(m_r - mnew);
      float p[16];
      float sum = 0.0f;
#pragma unroll
      for (int c = 0; c < 16; ++c) {
        p[c] = __expf(sv[c] - mnew);
        sum += p[c];
      }
      m_r = mnew;
      l_r = l_r * al + sum;
      alpha_s[row] = al;
      half8 p0, p1;
#pragma unroll
      for (int pr = 0; pr < 4; ++pr) {
        half2v h = pkrtz(p[2 * pr], p[2 * pr + 1]);
        p0[2 * pr] = h[0]; p0[2 * pr + 1] = h[1];
        half2v h2 = pkrtz(p[8 + 2 * pr], p[9 + 2 * pr]);
        p1[2 * pr] = h2[0]; p1[2 * pr + 1] = h2[1];
      }
      *(half8*)&PlL[row * PPAD] = p0;
      *(half8*)&PlL[row * PPAD + 8] = p1;
    }
    __syncthreads();

    // ---- PV: rescale O, accumulate P*V (upper 16 k-slots zero) ----
    {
      half8 pA = 0, pB = 0;
      if (quad < 2) {
        pA = *(const half8*)&PlL[l16 * PPAD + quad * 8];
        pB = *(const half8*)&PlL[(16 + l16) * PPAD + quad * 8];
      }
      float4v alA = *(const float4v*)&alpha_s[quad * 4];
      float4v alB = *(const float4v*)&alpha_s[16 + quad * 4];
#pragma unroll
      for (int t = 0; t < 8; ++t) {
        const int dcol = wave * 128 + t * 16 + l16;
        half8 vf = 0;
        if (quad < 2) vf = *(const half8*)&VtL[dcol * NK + quad * 8];
        acc[0][t] *= alA;
        acc[0][t] = __builtin_amdgcn_mfma_f32_16x16x32_f16(pA, vf, acc[0][t], 0, 0, 0);
        acc[1][t] *= alB;
        acc[1][t] = __builtin_amdgcn_mfma_f32_16x16x32_f16(pB, vf, acc[1][t], 0, 0, 0);
      }
    }
    __syncthreads();  // LDS reusable for next staging
  }

  if (wave < 2 && lane < 16) l_s[(wave << 4) + lane] = l_r;
  __syncthreads();

  // ---- epilogue ----
#pragma unroll
  for (int mt = 0; mt < 2; ++mt) {
    float4v lv = *(const float4v*)&l_s[mt * 16 + quad * 4];
    float4v linv = {1.0f / lv[0], 1.0f / lv[1], 1.0f / lv[2], 1.0f / lv[3]};
#pragma unroll
    for (int t = 0; t < 8; ++t) {
      size_t base = ((size_t)b * TQ + q0 + mt * 16 + quad * 4) * DIM +
                    wave * 128 + t * 16 + l16;
#pragma unroll
      for (int r = 0; r < 4; ++r) {
        out[base + (size_t)r * DIM] = acc[mt][t][r] * linv[r];
      }
    }
  }
}

extern "C" void kernel_launch(void* const* d_in, const int* in_sizes, int n_in,
                              void* d_out, int out_size, void* d_ws, size_t ws_size,
                              hipStream_t stream) {
  const float* dec = (const float*)d_in[0];
  const float* enc = (const float*)d_in[1];
  float* out = (float*)d_out;
  attn_flash2<<<dim3(BATCH * (TQ / MQ)), 256, 0, stream>>>(dec, enc, out);
}